// Round 1
// baseline (935.331 us; speedup 1.0000x reference)
//
#include <hip/hip_runtime.h>
#include <math.h>

#define NN 50000
#define NREL 400
#define NLAYERS 3

static __device__ __forceinline__ float clip15(float x) { return fminf(fmaxf(x, -15.f), 15.f); }

// ---------------- CSR build ----------------
__global__ void count_k(const int* __restrict__ dst, int* __restrict__ deg, int E) {
  int e = blockIdx.x * blockDim.x + threadIdx.x;
  if (e < E) atomicAdd(&deg[dst[e]], 1);
}

__global__ void scan_k(const int* __restrict__ deg, int* __restrict__ start, int* __restrict__ cursor,
                       int* __restrict__ counter, float* __restrict__ logsum, int N) {
  int n = blockIdx.x * blockDim.x + threadIdx.x;
  int lane = threadIdx.x & 63;
  int d = (n < N) ? deg[n] : 0;
  int pre = d;
  #pragma unroll
  for (int off = 1; off < 64; off <<= 1) { int t = __shfl_up(pre, off); if (lane >= off) pre += t; }
  int base = 0;
  if (lane == 63) base = atomicAdd(counter, pre);
  base = __shfl(base, 63);
  if (n < N) { int pos = base + pre - d; start[n] = pos; cursor[n] = pos; }
  float v = (n < N) ? logf((float)d + 1.0f) : 0.f;
  #pragma unroll
  for (int off = 32; off; off >>= 1) v += __shfl_xor(v, off);
  if (lane == 0) atomicAdd(logsum, v);
}

__global__ void scale_k(const int* __restrict__ deg, const float* __restrict__ logsum,
                        float* __restrict__ scale, int N) {
  int n = blockIdx.x * blockDim.x + threadIdx.x;
  if (n < N) scale[n] = logf((float)deg[n] + 1.0f) * (float)N / logsum[0];
}

__global__ void scatter_k(const int* __restrict__ src, const int* __restrict__ dst,
                          const int* __restrict__ typ, int* __restrict__ cursor,
                          int2* __restrict__ csr, int E) {
  int e = blockIdx.x * blockDim.x + threadIdx.x;
  if (e < E) {
    int dd = dst[e];
    int pos = atomicAdd(&cursor[dd], 1);
    csr[pos] = make_int2(src[e], typ[e]);
  }
}

// ---------------- init ----------------
// scalars layout: [0..63]=c_q (lin_b + q @ lin_W[64:128]) ; [64]=zero_s ; [65]=head_s
__global__ void prep_k(const float* __restrict__ head_embeds, const float* __restrict__ rel_table,
                       const float* __restrict__ lin_W, const float* __restrict__ lin_b,
                       const float* __restrict__ mlp_W1, const float* __restrict__ mlp_b1,
                       const float* __restrict__ mlp_W2, const float* __restrict__ mlp_b2,
                       const int* __restrict__ head_index, const int* __restrict__ r_index,
                       float* __restrict__ hidden, float* __restrict__ scalars) {
  int j = threadIdx.x;  // 0..63
  int r = r_index[0], hd = head_index[0];
  float qj = rel_table[r * 64 + j];
  float cq = lin_b[j];
  for (int k = 0; k < 64; ++k) cq += __shfl(qj, k) * lin_W[(64 + k) * 64 + j];
  scalars[j] = cq;
  // zero score: x = 0 -> h1 = relu(b1)
  float t = fmaxf(mlp_b1[j], 0.f) * mlp_W2[j] + fmaxf(mlp_b1[64 + j], 0.f) * mlp_W2[64 + j];
  #pragma unroll
  for (int off = 32; off; off >>= 1) t += __shfl_xor(t, off);
  float zs = clip15(t + mlp_b2[0]);
  // head node
  float hj = head_embeds[j];
  hidden[(size_t)hd * 64 + j] = hj;
  float heur = cq;
  for (int k = 0; k < 64; ++k) heur += __shfl(hj, k) * lin_W[k * 64 + j];
  float xj = hj * heur;
  float h1a = mlp_b1[j], h1b = mlp_b1[64 + j];
  for (int k = 0; k < 64; ++k) {
    float xk = __shfl(xj, k);
    h1a += xk * mlp_W1[k * 128 + j];
    h1b += xk * mlp_W1[k * 128 + 64 + j];
  }
  h1a = fmaxf(h1a, 0.f); h1b = fmaxf(h1b, 0.f);
  float p = h1a * mlp_W2[j] + h1b * mlp_W2[64 + j];
  #pragma unroll
  for (int off = 32; off; off >>= 1) p += __shfl_xor(p, off);
  float hs = clip15(p + mlp_b2[0]);
  if (j == 0) { scalars[64] = zs; scalars[65] = hs; }
}

__global__ void fill_k(float* __restrict__ score, const float* __restrict__ scalars,
                       const int* __restrict__ head_index, int N) {
  int n = blockIdx.x * blockDim.x + threadIdx.x;
  if (n < N) score[n] = (n == head_index[0]) ? scalars[65] : scalars[64];
}

// ---------------- per-layer ----------------
__global__ void gate_k(const float* __restrict__ hidden, const float* __restrict__ score,
                       float* __restrict__ LI, int N) {
  int i = blockIdx.x * blockDim.x + threadIdx.x;
  if (i < N * 16) {
    int node = i >> 4;
    float s = score[node];
    float g = 1.f / (1.f + expf(-s));
    float4 h = ((const float4*)hidden)[i];
    float4 r = make_float4(h.x * g, h.y * g, h.z * g, h.w * g);
    ((float4*)LI)[i] = r;
  }
}

// one wave per node; lane = dim
__global__ __launch_bounds__(256) void agg_k(const float* __restrict__ LI, const int2* __restrict__ csr,
                                             const int* __restrict__ start, const int* __restrict__ deg,
                                             const float* __restrict__ relW, float* __restrict__ f1, int N) {
  int wid = threadIdx.x >> 6;
  int lane = threadIdx.x & 63;
  int node = blockIdx.x * 4 + wid;
  if (node >= N) return;
  int base = start[node], d = deg[node];
  float sum = 0.f, sq = 0.f, mx = -3.402823e38f, mn = 3.402823e38f;
  int e = 0;
  for (; e + 2 <= d; e += 2) {
    int2 p0 = csr[base + e], p1 = csr[base + e + 1];
    float a0 = LI[p0.x * 64 + lane], w0 = relW[p0.y * 64 + lane];
    float a1 = LI[p1.x * 64 + lane], w1 = relW[p1.y * 64 + lane];
    float m0 = a0 * w0, m1 = a1 * w1;
    sum += m0 + m1; sq += m0 * m0 + m1 * m1;
    mx = fmaxf(mx, fmaxf(m0, m1)); mn = fminf(mn, fminf(m0, m1));
  }
  if (e < d) {
    int2 p = csr[base + e];
    float m = LI[p.x * 64 + lane] * relW[p.y * 64 + lane];
    sum += m; sq += m * m; mx = fmaxf(mx, m); mn = fminf(mn, m);
  }
  float* out = f1 + (size_t)node * 256;
  if (d > 0) {
    float inv = 1.0f / (float)d;
    float mean = sum * inv, sqm = sq * inv;
    float sd = sqrtf(fmaxf(sqm - mean * mean, 0.f) + 1e-6f);
    out[lane] = mean; out[64 + lane] = mx; out[128 + lane] = mn; out[192 + lane] = sd;
  } else {
    out[lane] = 0.f; out[64 + lane] = 0.f; out[128 + lane] = 0.f; out[192 + lane] = 0.f;
  }
}

// update = f1 @ Wa + scale*(f1 @ Wb) + b ; hidden += update (deg>0)
__global__ __launch_bounds__(256) void gemm_k(const float* __restrict__ f1, const float* __restrict__ aggW,
                                              const float* __restrict__ aggb, const float* __restrict__ scale,
                                              const int* __restrict__ deg, float* __restrict__ hidden, int N) {
  __shared__ float At[64][68];     // [kk][node], padded
  __shared__ float Ws[2][64 * 64]; // [kk][out] chunks of Wa, Wb
  int tid = threadIdx.x;
  int tx = tid & 63, ty = tid >> 6;  // tx = output dim, ty = 0..3
  int n0 = blockIdx.x * 64;
  float acc_a[16], acc_b[16];
  #pragma unroll
  for (int i = 0; i < 16; ++i) { acc_a[i] = 0.f; acc_b[i] = 0.f; }
  int r = tid >> 2, c0 = (tid & 3) << 4;
  bool rvalid = (n0 + r) < N;
  const float* Arow = f1 + (size_t)(n0 + r) * 256 + c0;
  for (int kc = 0; kc < 4; ++kc) {
    float4 v[4];
    if (rvalid) {
      const float4* ap = (const float4*)(Arow + kc * 64);
      #pragma unroll
      for (int s = 0; s < 4; ++s) v[s] = ap[s];
    } else {
      #pragma unroll
      for (int s = 0; s < 4; ++s) v[s] = make_float4(0.f, 0.f, 0.f, 0.f);
    }
    #pragma unroll
    for (int s = 0; s < 4; ++s) {
      At[c0 + s * 4 + 0][r] = v[s].x; At[c0 + s * 4 + 1][r] = v[s].y;
      At[c0 + s * 4 + 2][r] = v[s].z; At[c0 + s * 4 + 3][r] = v[s].w;
    }
    const float4* WaG = (const float4*)(aggW + (size_t)kc * 64 * 64);
    const float4* WbG = (const float4*)(aggW + (size_t)256 * 64 + (size_t)kc * 64 * 64);
    float4* WaS = (float4*)Ws[0];
    float4* WbS = (float4*)Ws[1];
    for (int i = tid; i < 1024; i += 256) { WaS[i] = WaG[i]; WbS[i] = WbG[i]; }
    __syncthreads();
    #pragma unroll 8
    for (int kk = 0; kk < 64; ++kk) {
      float wa = Ws[0][kk * 64 + tx], wb = Ws[1][kk * 64 + tx];
      const float4* arow = (const float4*)(&At[kk][ty << 4]);
      float4 a0 = arow[0], a1 = arow[1], a2 = arow[2], a3 = arow[3];
      acc_a[0] += a0.x * wa; acc_a[1] += a0.y * wa; acc_a[2] += a0.z * wa; acc_a[3] += a0.w * wa;
      acc_b[0] += a0.x * wb; acc_b[1] += a0.y * wb; acc_b[2] += a0.z * wb; acc_b[3] += a0.w * wb;
      acc_a[4] += a1.x * wa; acc_a[5] += a1.y * wa; acc_a[6] += a1.z * wa; acc_a[7] += a1.w * wa;
      acc_b[4] += a1.x * wb; acc_b[5] += a1.y * wb; acc_b[6] += a1.z * wb; acc_b[7] += a1.w * wb;
      acc_a[8] += a2.x * wa; acc_a[9] += a2.y * wa; acc_a[10] += a2.z * wa; acc_a[11] += a2.w * wa;
      acc_b[8] += a2.x * wb; acc_b[9] += a2.y * wb; acc_b[10] += a2.z * wb; acc_b[11] += a2.w * wb;
      acc_a[12] += a3.x * wa; acc_a[13] += a3.y * wa; acc_a[14] += a3.z * wa; acc_a[15] += a3.w * wa;
      acc_b[12] += a3.x * wb; acc_b[13] += a3.y * wb; acc_b[14] += a3.z * wb; acc_b[15] += a3.w * wb;
    }
    __syncthreads();
  }
  float bo = aggb[tx];
  #pragma unroll
  for (int i = 0; i < 16; ++i) {
    int node = n0 + (ty << 4) + i;
    if (node < N && deg[node] > 0) {
      float upd = acc_a[i] + scale[node] * acc_b[i] + bo;
      hidden[(size_t)node * 64 + tx] += upd;
    }
  }
}

// score update: one wave per node, weights staged in LDS
__global__ __launch_bounds__(256) void score_kl(const float* __restrict__ hidden, float* __restrict__ score,
                                                const int* __restrict__ deg, const float* __restrict__ lin_W,
                                                const float* __restrict__ mlp_W1, const float* __restrict__ mlp_b1,
                                                const float* __restrict__ mlp_W2, const float* __restrict__ mlp_b2,
                                                const float* __restrict__ scalars, int N) {
  __shared__ float sW1h[64 * 64];
  __shared__ float sW1[64 * 128];
  __shared__ float sW2[128], sb1[128], scq[64];
  int tid = threadIdx.x;
  for (int i = tid; i < 1024; i += 256) ((float4*)sW1h)[i] = ((const float4*)lin_W)[i];
  for (int i = tid; i < 2048; i += 256) ((float4*)sW1)[i] = ((const float4*)mlp_W1)[i];
  if (tid < 128) { sW2[tid] = mlp_W2[tid]; sb1[tid] = mlp_b1[tid]; }
  if (tid < 64) scq[tid] = scalars[tid];
  __syncthreads();
  float b2 = mlp_b2[0];
  int lane = tid & 63;
  int wid = (blockIdx.x * 256 + tid) >> 6;
  int nwaves = gridDim.x * 4;
  for (int node = wid; node < N; node += nwaves) {
    if (deg[node] <= 0) continue;
    float hj = hidden[(size_t)node * 64 + lane];
    float heur = scq[lane];
    for (int k = 0; k < 64; ++k) heur += __shfl(hj, k) * sW1h[k * 64 + lane];
    float xj = hj * heur;
    float h1a = sb1[lane], h1b = sb1[64 + lane];
    for (int k = 0; k < 64; ++k) {
      float xk = __shfl(xj, k);
      h1a += xk * sW1[k * 128 + lane];
      h1b += xk * sW1[k * 128 + 64 + lane];
    }
    h1a = fmaxf(h1a, 0.f); h1b = fmaxf(h1b, 0.f);
    float p = h1a * sW2[lane] + h1b * sW2[64 + lane];
    #pragma unroll
    for (int off = 32; off; off >>= 1) p += __shfl_xor(p, off);
    if (lane == 0) score[node] = p + b2;
  }
}

__global__ void out_k(const float* __restrict__ score, const int* __restrict__ t_index,
                      float* __restrict__ out, int T) {
  int i = blockIdx.x * blockDim.x + threadIdx.x;
  if (i < T) out[i] = score[t_index[i]];
}

// ---------------- launch ----------------
extern "C" void kernel_launch(void* const* d_in, const int* in_sizes, int n_in,
                              void* d_out, int out_size, void* d_ws, size_t ws_size,
                              hipStream_t stream) {
  const float* head_embeds = (const float*)d_in[0];
  const float* rel_table   = (const float*)d_in[1];
  const float* rel_W       = (const float*)d_in[2];
  const float* agg_W       = (const float*)d_in[3];
  const float* agg_b       = (const float*)d_in[4];
  const float* lin_W       = (const float*)d_in[5];
  const float* lin_b       = (const float*)d_in[6];
  const float* mlp_W1      = (const float*)d_in[7];
  const float* mlp_b1      = (const float*)d_in[8];
  const float* mlp_W2      = (const float*)d_in[9];
  const float* mlp_b2      = (const float*)d_in[10];
  const int* edge_src      = (const int*)d_in[11];
  const int* edge_dst      = (const int*)d_in[12];
  const int* edge_type     = (const int*)d_in[13];
  const int* head_index    = (const int*)d_in[14];
  const int* r_index       = (const int*)d_in[15];
  const int* t_index       = (const int*)d_in[16];
  int E = in_sizes[11];
  int T = in_sizes[16];
  int N = NN;

  char* w = (char*)d_ws;
  size_t off = 0;
  auto alloc = [&](size_t bytes) {
    void* p = w + off;
    off = (off + bytes + 255) & ~(size_t)255;
    return p;
  };
  int* deg      = (int*)alloc((size_t)N * 4);
  int* start    = (int*)alloc((size_t)N * 4);
  int* cursor   = (int*)alloc((size_t)N * 4);
  float* scale  = (float*)alloc((size_t)N * 4);
  int* counter  = (int*)alloc(4);
  float* logsum = (float*)alloc(4);
  float* scalars= (float*)alloc(66 * 4);
  int2* csr     = (int2*)alloc((size_t)E * 8);
  float* hidden = (float*)alloc((size_t)N * 64 * 4);
  float* score  = (float*)alloc((size_t)N * 4);
  float* LI     = (float*)alloc((size_t)N * 64 * 4);
  float* f1     = (float*)alloc((size_t)N * 256 * 4);
  if (off > ws_size) return;  // workspace too small -> fail loudly via wrong output

  hipMemsetAsync(deg, 0, (size_t)N * 4, stream);
  hipMemsetAsync(counter, 0, 4, stream);
  hipMemsetAsync(logsum, 0, 4, stream);
  hipMemsetAsync(hidden, 0, (size_t)N * 64 * 4, stream);

  count_k<<<(E + 255) / 256, 256, 0, stream>>>(edge_dst, deg, E);
  scan_k<<<(N + 255) / 256, 256, 0, stream>>>(deg, start, cursor, counter, logsum, N);
  scale_k<<<(N + 255) / 256, 256, 0, stream>>>(deg, logsum, scale, N);
  scatter_k<<<(E + 255) / 256, 256, 0, stream>>>(edge_src, edge_dst, edge_type, cursor, csr, E);
  prep_k<<<1, 64, 0, stream>>>(head_embeds, rel_table, lin_W, lin_b, mlp_W1, mlp_b1, mlp_W2, mlp_b2,
                               head_index, r_index, hidden, scalars);
  fill_k<<<(N + 255) / 256, 256, 0, stream>>>(score, scalars, head_index, N);

  for (int l = 0; l < NLAYERS; ++l) {
    gate_k<<<(N * 16 + 255) / 256, 256, 0, stream>>>(hidden, score, LI, N);
    agg_k<<<(N + 3) / 4, 256, 0, stream>>>(LI, csr, start, deg, rel_W + (size_t)l * NREL * 64, f1, N);
    gemm_k<<<(N + 63) / 64, 256, 0, stream>>>(f1, agg_W + (size_t)l * 512 * 64, agg_b + (size_t)l * 64,
                                              scale, deg, hidden, N);
    score_kl<<<1024, 256, 0, stream>>>(hidden, score, deg, lin_W, mlp_W1, mlp_b1, mlp_W2, mlp_b2, scalars, N);
  }
  out_k<<<(T + 255) / 256, 256, 0, stream>>>(score, t_index, (float*)d_out, T);
}

// Round 5
// 670.147 us; speedup vs baseline: 1.3957x; 1.3957x over previous
//
#include <hip/hip_runtime.h>
#include <math.h>

#define NN 50000
#define NREL 400
#define NLAYERS 3

static __device__ __forceinline__ float clip15(float x) { return fminf(fmaxf(x, -15.f), 15.f); }

// ---------------- CSR build ----------------
__global__ void count_k(const int* __restrict__ dst, int* __restrict__ deg, int E) {
  int e = blockIdx.x * blockDim.x + threadIdx.x;
  if (e < E) atomicAdd(&deg[dst[e]], 1);
}

__global__ void scan_k(const int* __restrict__ deg, int* __restrict__ start, int* __restrict__ cursor,
                       int* __restrict__ counter, float* __restrict__ logsum, int N) {
  int n = blockIdx.x * blockDim.x + threadIdx.x;
  int lane = threadIdx.x & 63;
  int d = (n < N) ? deg[n] : 0;
  int pre = d;
  #pragma unroll
  for (int off = 1; off < 64; off <<= 1) { int t = __shfl_up(pre, off); if (lane >= off) pre += t; }
  int base = 0;
  if (lane == 63) base = atomicAdd(counter, pre);
  base = __shfl(base, 63);
  if (n < N) { int pos = base + pre - d; start[n] = pos; cursor[n] = pos; }
  float v = (n < N) ? logf((float)d + 1.0f) : 0.f;
  #pragma unroll
  for (int off = 32; off; off >>= 1) v += __shfl_xor(v, off);
  if (lane == 0) atomicAdd(logsum, v);
}

__global__ void scale_k(const int* __restrict__ deg, const float* __restrict__ logsum,
                        float* __restrict__ scale, int N) {
  int n = blockIdx.x * blockDim.x + threadIdx.x;
  if (n < N) scale[n] = logf((float)deg[n] + 1.0f) * (float)N / logsum[0];
}

__global__ void scatter_k(const int* __restrict__ src, const int* __restrict__ dst,
                          const int* __restrict__ typ, int* __restrict__ cursor,
                          int2* __restrict__ csr, int E) {
  int e = blockIdx.x * blockDim.x + threadIdx.x;
  if (e < E) {
    int dd = dst[e];
    int pos = atomicAdd(&cursor[dd], 1);
    csr[pos] = make_int2(src[e], typ[e]);
  }
}

// ---------------- init ----------------
// scalars layout: [0..63]=c_q (lin_b + q @ lin_W[64:128]) ; [64]=zero_s ; [65]=head_s
__global__ void prep_k(const float* __restrict__ head_embeds, const float* __restrict__ rel_table,
                       const float* __restrict__ lin_W, const float* __restrict__ lin_b,
                       const float* __restrict__ mlp_W1, const float* __restrict__ mlp_b1,
                       const float* __restrict__ mlp_W2, const float* __restrict__ mlp_b2,
                       const int* __restrict__ head_index, const int* __restrict__ r_index,
                       float* __restrict__ hidden, float* __restrict__ scalars) {
  int j = threadIdx.x;  // 0..63
  int r = r_index[0], hd = head_index[0];
  float qj = rel_table[r * 64 + j];
  float cq = lin_b[j];
  for (int k = 0; k < 64; ++k) cq += __shfl(qj, k) * lin_W[(64 + k) * 64 + j];
  scalars[j] = cq;
  // zero score: x = 0 -> h1 = relu(b1)
  float t = fmaxf(mlp_b1[j], 0.f) * mlp_W2[j] + fmaxf(mlp_b1[64 + j], 0.f) * mlp_W2[64 + j];
  #pragma unroll
  for (int off = 32; off; off >>= 1) t += __shfl_xor(t, off);
  float zs = clip15(t + mlp_b2[0]);
  // head node
  float hj = head_embeds[j];
  hidden[(size_t)hd * 64 + j] = hj;
  float heur = cq;
  for (int k = 0; k < 64; ++k) heur += __shfl(hj, k) * lin_W[k * 64 + j];
  float xj = hj * heur;
  float h1a = mlp_b1[j], h1b = mlp_b1[64 + j];
  for (int k = 0; k < 64; ++k) {
    float xk = __shfl(xj, k);
    h1a += xk * mlp_W1[k * 128 + j];
    h1b += xk * mlp_W1[k * 128 + 64 + j];
  }
  h1a = fmaxf(h1a, 0.f); h1b = fmaxf(h1b, 0.f);
  float p = h1a * mlp_W2[j] + h1b * mlp_W2[64 + j];
  #pragma unroll
  for (int off = 32; off; off >>= 1) p += __shfl_xor(p, off);
  float hs = clip15(p + mlp_b2[0]);
  if (j == 0) { scalars[64] = zs; scalars[65] = hs; }
}

__global__ void fill_k(float* __restrict__ score, const float* __restrict__ scalars,
                       const int* __restrict__ head_index, int N) {
  int n = blockIdx.x * blockDim.x + threadIdx.x;
  if (n < N) score[n] = (n == head_index[0]) ? scalars[65] : scalars[64];
}

// ---------------- per-layer ----------------
__global__ void gate_k(const float* __restrict__ hidden, const float* __restrict__ score,
                       float* __restrict__ LI, int N) {
  int i = blockIdx.x * blockDim.x + threadIdx.x;
  if (i < N * 16) {
    int node = i >> 4;
    float s = score[node];
    float g = 1.f / (1.f + expf(-s));
    float4 h = ((const float4*)hidden)[i];
    float4 r = make_float4(h.x * g, h.y * g, h.z * g, h.w * g);
    ((float4*)LI)[i] = r;
  }
}

// one wave per node; lane = dim; 4-wide edge unroll for MLP
__global__ __launch_bounds__(256) void agg_k(const float* __restrict__ LI, const int2* __restrict__ csr,
                                             const int* __restrict__ start, const int* __restrict__ deg,
                                             const float* __restrict__ relW, float* __restrict__ f1, int N) {
  int wid = threadIdx.x >> 6;
  int lane = threadIdx.x & 63;
  int node = blockIdx.x * 4 + wid;
  if (node >= N) return;
  int base = start[node], d = deg[node];
  float sum = 0.f, sq = 0.f, mx = -3.402823e38f, mn = 3.402823e38f;
  int e = 0;
  for (; e + 4 <= d; e += 4) {
    int2 p0 = csr[base + e], p1 = csr[base + e + 1];
    int2 p2 = csr[base + e + 2], p3 = csr[base + e + 3];
    float a0 = LI[p0.x * 64 + lane], w0 = relW[p0.y * 64 + lane];
    float a1 = LI[p1.x * 64 + lane], w1 = relW[p1.y * 64 + lane];
    float a2 = LI[p2.x * 64 + lane], w2 = relW[p2.y * 64 + lane];
    float a3 = LI[p3.x * 64 + lane], w3 = relW[p3.y * 64 + lane];
    float m0 = a0 * w0, m1 = a1 * w1, m2 = a2 * w2, m3 = a3 * w3;
    sum += (m0 + m1) + (m2 + m3);
    sq += (m0 * m0 + m1 * m1) + (m2 * m2 + m3 * m3);
    mx = fmaxf(fmaxf(mx, fmaxf(m0, m1)), fmaxf(m2, m3));
    mn = fminf(fminf(mn, fminf(m0, m1)), fminf(m2, m3));
  }
  for (; e < d; ++e) {
    int2 p = csr[base + e];
    float m = LI[p.x * 64 + lane] * relW[p.y * 64 + lane];
    sum += m; sq += m * m; mx = fmaxf(mx, m); mn = fminf(mn, m);
  }
  float* out = f1 + (size_t)node * 256;
  if (d > 0) {
    float inv = 1.0f / (float)d;
    float mean = sum * inv, sqm = sq * inv;
    float sd = sqrtf(fmaxf(sqm - mean * mean, 0.f) + 1e-6f);
    out[lane] = mean; out[64 + lane] = mx; out[128 + lane] = mn; out[192 + lane] = sd;
  } else {
    out[lane] = 0.f; out[64 + lane] = 0.f; out[128 + lane] = 0.f; out[192 + lane] = 0.f;
  }
}

// update = f1 @ Wa + scale*(f1 @ Wb) + b ; hidden += update (deg>0)
__global__ __launch_bounds__(256) void gemm_k(const float* __restrict__ f1, const float* __restrict__ aggW,
                                              const float* __restrict__ aggb, const float* __restrict__ scale,
                                              const int* __restrict__ deg, float* __restrict__ hidden, int N) {
  __shared__ float At[64][68];     // [kk][node], padded
  __shared__ float Ws[2][64 * 64]; // [kk][out] chunks of Wa, Wb
  int tid = threadIdx.x;
  int tx = tid & 63, ty = tid >> 6;  // tx = output dim, ty = 0..3
  int n0 = blockIdx.x * 64;
  float acc_a[16], acc_b[16];
  #pragma unroll
  for (int i = 0; i < 16; ++i) { acc_a[i] = 0.f; acc_b[i] = 0.f; }
  int r = tid >> 2, c0 = (tid & 3) << 4;
  bool rvalid = (n0 + r) < N;
  const float* Arow = f1 + (size_t)(n0 + r) * 256 + c0;
  for (int kc = 0; kc < 4; ++kc) {
    float4 v[4];
    if (rvalid) {
      const float4* ap = (const float4*)(Arow + kc * 64);
      #pragma unroll
      for (int s = 0; s < 4; ++s) v[s] = ap[s];
    } else {
      #pragma unroll
      for (int s = 0; s < 4; ++s) v[s] = make_float4(0.f, 0.f, 0.f, 0.f);
    }
    #pragma unroll
    for (int s = 0; s < 4; ++s) {
      At[c0 + s * 4 + 0][r] = v[s].x; At[c0 + s * 4 + 1][r] = v[s].y;
      At[c0 + s * 4 + 2][r] = v[s].z; At[c0 + s * 4 + 3][r] = v[s].w;
    }
    const float4* WaG = (const float4*)(aggW + (size_t)kc * 64 * 64);
    const float4* WbG = (const float4*)(aggW + (size_t)256 * 64 + (size_t)kc * 64 * 64);
    float4* WaS = (float4*)Ws[0];
    float4* WbS = (float4*)Ws[1];
    for (int i = tid; i < 1024; i += 256) { WaS[i] = WaG[i]; WbS[i] = WbG[i]; }
    __syncthreads();
    #pragma unroll 8
    for (int kk = 0; kk < 64; ++kk) {
      float wa = Ws[0][kk * 64 + tx], wb = Ws[1][kk * 64 + tx];
      const float4* arow = (const float4*)(&At[kk][ty << 4]);
      float4 a0 = arow[0], a1 = arow[1], a2 = arow[2], a3 = arow[3];
      acc_a[0] += a0.x * wa; acc_a[1] += a0.y * wa; acc_a[2] += a0.z * wa; acc_a[3] += a0.w * wa;
      acc_b[0] += a0.x * wb; acc_b[1] += a0.y * wb; acc_b[2] += a0.z * wb; acc_b[3] += a0.w * wb;
      acc_a[4] += a1.x * wa; acc_a[5] += a1.y * wa; acc_a[6] += a1.z * wa; acc_a[7] += a1.w * wa;
      acc_b[4] += a1.x * wb; acc_b[5] += a1.y * wb; acc_b[6] += a1.z * wb; acc_b[7] += a1.w * wb;
      acc_a[8] += a2.x * wa; acc_a[9] += a2.y * wa; acc_a[10] += a2.z * wa; acc_a[11] += a2.w * wa;
      acc_b[8] += a2.x * wb; acc_b[9] += a2.y * wb; acc_b[10] += a2.z * wb; acc_b[11] += a2.w * wb;
      acc_a[12] += a3.x * wa; acc_a[13] += a3.y * wa; acc_a[14] += a3.z * wa; acc_a[15] += a3.w * wa;
      acc_b[12] += a3.x * wb; acc_b[13] += a3.y * wb; acc_b[14] += a3.z * wb; acc_b[15] += a3.w * wb;
    }
    __syncthreads();
  }
  float bo = aggb[tx];
  #pragma unroll
  for (int i = 0; i < 16; ++i) {
    int node = n0 + (ty << 4) + i;
    if (node < N && deg[node] > 0) {
      float upd = acc_a[i] + scale[node] * acc_b[i] + bo;
      hidden[(size_t)node * 64 + tx] += upd;
    }
  }
}

// ---------------- score: register-blocked tile kernel ----------------
// 64 nodes per block, 256 threads. lane = node (0..63), g = tid>>6 (0..3).
// Phase A: heur = H @ lin_W[0:64] + cq, x = H * heur (16 indep acc/thread).
// Phase B: h1 = relu(x @ W1 + b1), p = sum(h1 * W2) (32 indep acc/thread).
// LDS layout (floats), phase-overlapped:
//   X  @ 0     (64*65 = 4160)
//   H  @ 4160  (4160)           } phase A
//   WA @ 8320  (4096)           } phase A (lin_W rows 0..63)
//   W1 @ 4160  (8192)           } phase B (overwrites H+WA after sync)
//   sW2 @ 12416 (128), sb1 @ 12544 (128), scq @ 12672 (64), pred @ 12736 (256)
#define SC_LDS 12992
__global__ __launch_bounds__(256) void score2_k(const float* __restrict__ hidden, float* __restrict__ score,
                                                const int* __restrict__ deg, const float* __restrict__ lin_W,
                                                const float* __restrict__ mlp_W1, const float* __restrict__ mlp_b1,
                                                const float* __restrict__ mlp_W2, const float* __restrict__ mlp_b2,
                                                const float* __restrict__ scalars, int N) {
  __shared__ float smem[SC_LDS];
  float* X   = smem;
  float* H   = smem + 4160;
  float* WA  = smem + 8320;
  float* W1s = smem + 4160;
  float* sW2 = smem + 12416;
  float* sb1 = smem + 12544;
  float* scq = smem + 12672;
  float* pred= smem + 12736;

  int t = threadIdx.x;
  int lane = t & 63;        // node within tile
  int g = t >> 6;           // 0..3
  int n0 = blockIdx.x * 64;

  // stage lin_W rows 0..63 (hidden part), smalls
  for (int i = t; i < 1024; i += 256) ((float4*)WA)[i] = ((const float4*)lin_W)[i];
  if (t < 128) { sW2[t] = mlp_W2[t]; sb1[t] = mlp_b1[t]; }
  if (t < 64) scq[t] = scalars[t];
  // stage hidden tile -> H[node][k] with stride 65
  for (int i = t; i < 1024; i += 256) {
    int node = i >> 4;
    int k4 = (i & 15) << 2;
    float4 v = make_float4(0.f, 0.f, 0.f, 0.f);
    if (n0 + node < N) v = ((const float4*)(hidden + (size_t)(n0 + node) * 64))[i & 15];
    float* hp = &H[node * 65 + k4];
    hp[0] = v.x; hp[1] = v.y; hp[2] = v.z; hp[3] = v.w;
  }
  __syncthreads();

  // Phase A: heur (16 outputs j = g*16 + i per thread, node = lane)
  float acc[16];
  #pragma unroll
  for (int i = 0; i < 16; ++i) acc[i] = scq[g * 16 + i];
  #pragma unroll 8
  for (int kk = 0; kk < 64; ++kk) {
    float h = H[lane * 65 + kk];                       // 2-way alias: free
    const float4* wr = (const float4*)&WA[kk * 64 + g * 16];  // broadcast
    float4 w0 = wr[0], w1 = wr[1], w2 = wr[2], w3 = wr[3];
    acc[0]  += h * w0.x; acc[1]  += h * w0.y; acc[2]  += h * w0.z; acc[3]  += h * w0.w;
    acc[4]  += h * w1.x; acc[5]  += h * w1.y; acc[6]  += h * w1.z; acc[7]  += h * w1.w;
    acc[8]  += h * w2.x; acc[9]  += h * w2.y; acc[10] += h * w2.z; acc[11] += h * w2.w;
    acc[12] += h * w3.x; acc[13] += h * w3.y; acc[14] += h * w3.z; acc[15] += h * w3.w;
  }
  // x = H * heur, store to X
  #pragma unroll
  for (int i = 0; i < 16; ++i) {
    int j = g * 16 + i;
    X[lane * 65 + j] = H[lane * 65 + j] * acc[i];
  }
  __syncthreads();  // X complete; H/WA now dead

  // stage W1 (64x128) into the H/WA region
  for (int i = t; i < 2048; i += 256) ((float4*)W1s)[i] = ((const float4*)mlp_W1)[i];
  __syncthreads();

  // Phase B: h1 j2 = g*32 + i, node = lane
  float acc2[32];
  #pragma unroll
  for (int i = 0; i < 32; ++i) acc2[i] = sb1[g * 32 + i];
  #pragma unroll 4
  for (int kk = 0; kk < 64; ++kk) {
    float xv = X[lane * 65 + kk];
    const float4* wr = (const float4*)&W1s[kk * 128 + g * 32];  // broadcast
    #pragma unroll
    for (int s = 0; s < 8; ++s) {
      float4 w = wr[s];
      acc2[s * 4 + 0] += xv * w.x; acc2[s * 4 + 1] += xv * w.y;
      acc2[s * 4 + 2] += xv * w.z; acc2[s * 4 + 3] += xv * w.w;
    }
  }
  float p = 0.f;
  #pragma unroll
  for (int i = 0; i < 32; ++i) p += fmaxf(acc2[i], 0.f) * sW2[g * 32 + i];
  pred[g * 64 + lane] = p;
  __syncthreads();
  if (t < 64) {
    int node = n0 + t;
    if (node < N && deg[node] > 0)
      score[node] = pred[t] + pred[64 + t] + pred[128 + t] + pred[192 + t] + mlp_b2[0];
  }
}

__global__ void out_k(const float* __restrict__ score, const int* __restrict__ t_index,
                      float* __restrict__ out, int T) {
  int i = blockIdx.x * blockDim.x + threadIdx.x;
  if (i < T) out[i] = score[t_index[i]];
}

// ---------------- launch ----------------
extern "C" void kernel_launch(void* const* d_in, const int* in_sizes, int n_in,
                              void* d_out, int out_size, void* d_ws, size_t ws_size,
                              hipStream_t stream) {
  const float* head_embeds = (const float*)d_in[0];
  const float* rel_table   = (const float*)d_in[1];
  const float* rel_W       = (const float*)d_in[2];
  const float* agg_W       = (const float*)d_in[3];
  const float* agg_b       = (const float*)d_in[4];
  const float* lin_W       = (const float*)d_in[5];
  const float* lin_b       = (const float*)d_in[6];
  const float* mlp_W1      = (const float*)d_in[7];
  const float* mlp_b1      = (const float*)d_in[8];
  const float* mlp_W2      = (const float*)d_in[9];
  const float* mlp_b2      = (const float*)d_in[10];
  const int* edge_src      = (const int*)d_in[11];
  const int* edge_dst      = (const int*)d_in[12];
  const int* edge_type     = (const int*)d_in[13];
  const int* head_index    = (const int*)d_in[14];
  const int* r_index       = (const int*)d_in[15];
  const int* t_index       = (const int*)d_in[16];
  int E = in_sizes[11];
  int T = in_sizes[16];
  int N = NN;

  char* w = (char*)d_ws;
  size_t off = 0;
  auto alloc = [&](size_t bytes) {
    void* p = w + off;
    off = (off + bytes + 255) & ~(size_t)255;
    return p;
  };
  int* deg      = (int*)alloc((size_t)N * 4);
  int* start    = (int*)alloc((size_t)N * 4);
  int* cursor   = (int*)alloc((size_t)N * 4);
  float* scale  = (float*)alloc((size_t)N * 4);
  int* counter  = (int*)alloc(4);
  float* logsum = (float*)alloc(4);
  float* scalars= (float*)alloc(66 * 4);
  int2* csr     = (int2*)alloc((size_t)E * 8);
  float* hidden = (float*)alloc((size_t)N * 64 * 4);
  float* score  = (float*)alloc((size_t)N * 4);
  float* LI     = (float*)alloc((size_t)N * 64 * 4);
  float* f1     = (float*)alloc((size_t)N * 256 * 4);
  if (off > ws_size) return;  // workspace too small -> fail loudly via wrong output

  hipMemsetAsync(deg, 0, (size_t)N * 4, stream);
  hipMemsetAsync(counter, 0, 4, stream);
  hipMemsetAsync(logsum, 0, 4, stream);
  hipMemsetAsync(hidden, 0, (size_t)N * 64 * 4, stream);

  count_k<<<(E + 255) / 256, 256, 0, stream>>>(edge_dst, deg, E);
  scan_k<<<(N + 255) / 256, 256, 0, stream>>>(deg, start, cursor, counter, logsum, N);
  scale_k<<<(N + 255) / 256, 256, 0, stream>>>(deg, logsum, scale, N);
  scatter_k<<<(E + 255) / 256, 256, 0, stream>>>(edge_src, edge_dst, edge_type, cursor, csr, E);
  prep_k<<<1, 64, 0, stream>>>(head_embeds, rel_table, lin_W, lin_b, mlp_W1, mlp_b1, mlp_W2, mlp_b2,
                               head_index, r_index, hidden, scalars);
  fill_k<<<(N + 255) / 256, 256, 0, stream>>>(score, scalars, head_index, N);

  for (int l = 0; l < NLAYERS; ++l) {
    gate_k<<<(N * 16 + 255) / 256, 256, 0, stream>>>(hidden, score, LI, N);
    agg_k<<<(N + 3) / 4, 256, 0, stream>>>(LI, csr, start, deg, rel_W + (size_t)l * NREL * 64, f1, N);
    gemm_k<<<(N + 63) / 64, 256, 0, stream>>>(f1, agg_W + (size_t)l * 512 * 64, agg_b + (size_t)l * 64,
                                              scale, deg, hidden, N);
    score2_k<<<(N + 63) / 64, 256, 0, stream>>>(hidden, score, deg, lin_W, mlp_W1, mlp_b1, mlp_W2, mlp_b2,
                                                scalars, N);
  }
  out_k<<<(T + 255) / 256, 256, 0, stream>>>(score, t_index, (float*)d_out, T);
}

// Round 6
// 594.476 us; speedup vs baseline: 1.5734x; 1.1273x over previous
//
#include <hip/hip_runtime.h>
#include <math.h>

#define NN 50000
#define NREL 400
#define NLAYERS 3

static __device__ __forceinline__ float clip15(float x) { return fminf(fmaxf(x, -15.f), 15.f); }

// ---------------- CSR build ----------------
__global__ void count_k(const int* __restrict__ dst, int* __restrict__ deg, int E) {
  int e = blockIdx.x * blockDim.x + threadIdx.x;
  if (e < E) atomicAdd(&deg[dst[e]], 1);
}

__global__ void scan_k(const int* __restrict__ deg, int* __restrict__ start, int* __restrict__ cursor,
                       int* __restrict__ counter, float* __restrict__ logsum, int N) {
  int n = blockIdx.x * blockDim.x + threadIdx.x;
  int lane = threadIdx.x & 63;
  int d = (n < N) ? deg[n] : 0;
  int pre = d;
  #pragma unroll
  for (int off = 1; off < 64; off <<= 1) { int t = __shfl_up(pre, off); if (lane >= off) pre += t; }
  int base = 0;
  if (lane == 63) base = atomicAdd(counter, pre);
  base = __shfl(base, 63);
  if (n < N) { int pos = base + pre - d; start[n] = pos; cursor[n] = pos; }
  float v = (n < N) ? logf((float)d + 1.0f) : 0.f;
  #pragma unroll
  for (int off = 32; off; off >>= 1) v += __shfl_xor(v, off);
  if (lane == 0) atomicAdd(logsum, v);
}

__global__ void scale_k(const int* __restrict__ deg, const float* __restrict__ logsum,
                        float* __restrict__ scale, int N) {
  int n = blockIdx.x * blockDim.x + threadIdx.x;
  if (n < N) scale[n] = logf((float)deg[n] + 1.0f) * (float)N / logsum[0];
}

__global__ void scatter_k(const int* __restrict__ src, const int* __restrict__ dst,
                          const int* __restrict__ typ, int* __restrict__ cursor,
                          int2* __restrict__ csr, int E) {
  int e = blockIdx.x * blockDim.x + threadIdx.x;
  if (e < E) {
    int dd = dst[e];
    int pos = atomicAdd(&cursor[dd], 1);
    csr[pos] = make_int2(src[e], typ[e]);
  }
}

// ---------------- init ----------------
// scalars layout: [0..63]=c_q (lin_b + q @ lin_W[64:128]) ; [64]=zero_s ; [65]=head_s
__global__ void prep_k(const float* __restrict__ head_embeds, const float* __restrict__ rel_table,
                       const float* __restrict__ lin_W, const float* __restrict__ lin_b,
                       const float* __restrict__ mlp_W1, const float* __restrict__ mlp_b1,
                       const float* __restrict__ mlp_W2, const float* __restrict__ mlp_b2,
                       const int* __restrict__ head_index, const int* __restrict__ r_index,
                       float* __restrict__ hidden, float* __restrict__ scalars) {
  int j = threadIdx.x;  // 0..63
  int r = r_index[0], hd = head_index[0];
  float qj = rel_table[r * 64 + j];
  float cq = lin_b[j];
  for (int k = 0; k < 64; ++k) cq += __shfl(qj, k) * lin_W[(64 + k) * 64 + j];
  scalars[j] = cq;
  // zero score: x = 0 -> h1 = relu(b1)
  float t = fmaxf(mlp_b1[j], 0.f) * mlp_W2[j] + fmaxf(mlp_b1[64 + j], 0.f) * mlp_W2[64 + j];
  #pragma unroll
  for (int off = 32; off; off >>= 1) t += __shfl_xor(t, off);
  float zs = clip15(t + mlp_b2[0]);
  // head node
  float hj = head_embeds[j];
  hidden[(size_t)hd * 64 + j] = hj;
  float heur = cq;
  for (int k = 0; k < 64; ++k) heur += __shfl(hj, k) * lin_W[k * 64 + j];
  float xj = hj * heur;
  float h1a = mlp_b1[j], h1b = mlp_b1[64 + j];
  for (int k = 0; k < 64; ++k) {
    float xk = __shfl(xj, k);
    h1a += xk * mlp_W1[k * 128 + j];
    h1b += xk * mlp_W1[k * 128 + 64 + j];
  }
  h1a = fmaxf(h1a, 0.f); h1b = fmaxf(h1b, 0.f);
  float p = h1a * mlp_W2[j] + h1b * mlp_W2[64 + j];
  #pragma unroll
  for (int off = 32; off; off >>= 1) p += __shfl_xor(p, off);
  float hs = clip15(p + mlp_b2[0]);
  if (j == 0) { scalars[64] = zs; scalars[65] = hs; }
}

__global__ void fill_k(float* __restrict__ score, const float* __restrict__ scalars,
                       const int* __restrict__ head_index, int N) {
  int n = blockIdx.x * blockDim.x + threadIdx.x;
  if (n < N) score[n] = (n == head_index[0]) ? scalars[65] : scalars[64];
}

// ---------------- per-layer ----------------
__global__ void gate_k(const float* __restrict__ hidden, const float* __restrict__ score,
                       float* __restrict__ LI, int N) {
  int i = blockIdx.x * blockDim.x + threadIdx.x;
  if (i < N * 16) {
    int node = i >> 4;
    float s = score[node];
    float g = 1.f / (1.f + expf(-s));
    float4 h = ((const float4*)hidden)[i];
    float4 r = make_float4(h.x * g, h.y * g, h.z * g, h.w * g);
    ((float4*)LI)[i] = r;
  }
}

// one wave per node; lane = dim; 4-wide edge unroll for MLP
__global__ __launch_bounds__(256) void agg_k(const float* __restrict__ LI, const int2* __restrict__ csr,
                                             const int* __restrict__ start, const int* __restrict__ deg,
                                             const float* __restrict__ relW, float* __restrict__ f1, int N) {
  int wid = threadIdx.x >> 6;
  int lane = threadIdx.x & 63;
  int node = blockIdx.x * 4 + wid;
  if (node >= N) return;
  int base = start[node], d = deg[node];
  float sum = 0.f, sq = 0.f, mx = -3.402823e38f, mn = 3.402823e38f;
  int e = 0;
  for (; e + 4 <= d; e += 4) {
    int2 p0 = csr[base + e], p1 = csr[base + e + 1];
    int2 p2 = csr[base + e + 2], p3 = csr[base + e + 3];
    float a0 = LI[p0.x * 64 + lane], w0 = relW[p0.y * 64 + lane];
    float a1 = LI[p1.x * 64 + lane], w1 = relW[p1.y * 64 + lane];
    float a2 = LI[p2.x * 64 + lane], w2 = relW[p2.y * 64 + lane];
    float a3 = LI[p3.x * 64 + lane], w3 = relW[p3.y * 64 + lane];
    float m0 = a0 * w0, m1 = a1 * w1, m2 = a2 * w2, m3 = a3 * w3;
    sum += (m0 + m1) + (m2 + m3);
    sq += (m0 * m0 + m1 * m1) + (m2 * m2 + m3 * m3);
    mx = fmaxf(fmaxf(mx, fmaxf(m0, m1)), fmaxf(m2, m3));
    mn = fminf(fminf(mn, fminf(m0, m1)), fminf(m2, m3));
  }
  for (; e < d; ++e) {
    int2 p = csr[base + e];
    float m = LI[p.x * 64 + lane] * relW[p.y * 64 + lane];
    sum += m; sq += m * m; mx = fmaxf(mx, m); mn = fminf(mn, m);
  }
  float* out = f1 + (size_t)node * 256;
  if (d > 0) {
    float inv = 1.0f / (float)d;
    float mean = sum * inv, sqm = sq * inv;
    float sd = sqrtf(fmaxf(sqm - mean * mean, 0.f) + 1e-6f);
    out[lane] = mean; out[64 + lane] = mx; out[128 + lane] = mn; out[192 + lane] = sd;
  } else {
    out[lane] = 0.f; out[64 + lane] = 0.f; out[128 + lane] = 0.f; out[192 + lane] = 0.f;
  }
}

// update = f1 @ Wa + scale*(f1 @ Wb) + b ; hidden += update (deg>0)
// Register-blocked: 256 thr, C-tile 64 nodes x 64 outs, thread = 4n x 4o x {a,b} (32 acc).
// K-chunks of 32: At[32][68] transposed + Was/Wbs[32][64] = 24.5 KB LDS (6 blocks/CU cap).
// Inner kk: 3x ds_read_b128 (12 floats) per 32 FMA -> VALU-bound.
__global__ __launch_bounds__(256) void gemm_k(const float* __restrict__ f1, const float* __restrict__ aggW,
                                              const float* __restrict__ aggb, const float* __restrict__ scale,
                                              const int* __restrict__ deg, float* __restrict__ hidden, int N) {
  __shared__ float At[32][68];   // [k][node], stride 68 keeps 16B alignment
  __shared__ float Was[32][64];
  __shared__ float Wbs[32][64];
  int tid = threadIdx.x;
  int tx = tid & 15;    // out group: outs tx*4..tx*4+3
  int tn = tid >> 4;    // node group: nodes tn*4..tn*4+3
  int n0 = blockIdx.x * 64;
  float acc_a[4][4] = {{0.f}}, acc_b[4][4] = {{0.f}};
  // A staging mapping: thread -> node = tid>>2 (0..63), k-offset = (tid&3)*8
  int anode = tid >> 2;
  int ak = (tid & 3) * 8;
  bool avalid = (n0 + anode) < N;
  const float* Arow = f1 + (size_t)(n0 + anode) * 256 + ak;
  for (int kc = 0; kc < 8; ++kc) {
    float4 v0 = make_float4(0.f, 0.f, 0.f, 0.f), v1 = v0;
    if (avalid) {
      const float4* ap = (const float4*)(Arow + kc * 32);
      v0 = ap[0]; v1 = ap[1];
    }
    At[ak + 0][anode] = v0.x; At[ak + 1][anode] = v0.y;
    At[ak + 2][anode] = v0.z; At[ak + 3][anode] = v0.w;
    At[ak + 4][anode] = v1.x; At[ak + 5][anode] = v1.y;
    At[ak + 6][anode] = v1.z; At[ak + 7][anode] = v1.w;
    const float4* WaG = (const float4*)(aggW + (size_t)(kc * 32) * 64);
    const float4* WbG = (const float4*)(aggW + (size_t)(256 + kc * 32) * 64);
    ((float4*)Was)[tid] = WaG[tid];
    ((float4*)Was)[tid + 256] = WaG[tid + 256];
    ((float4*)Wbs)[tid] = WbG[tid];
    ((float4*)Wbs)[tid + 256] = WbG[tid + 256];
    __syncthreads();
    #pragma unroll 8
    for (int kk = 0; kk < 32; ++kk) {
      float4 a  = *(const float4*)&At[kk][tn * 4];
      float4 wa = *(const float4*)&Was[kk][tx * 4];
      float4 wb = *(const float4*)&Wbs[kk][tx * 4];
      acc_a[0][0] += a.x * wa.x; acc_a[0][1] += a.x * wa.y; acc_a[0][2] += a.x * wa.z; acc_a[0][3] += a.x * wa.w;
      acc_a[1][0] += a.y * wa.x; acc_a[1][1] += a.y * wa.y; acc_a[1][2] += a.y * wa.z; acc_a[1][3] += a.y * wa.w;
      acc_a[2][0] += a.z * wa.x; acc_a[2][1] += a.z * wa.y; acc_a[2][2] += a.z * wa.z; acc_a[2][3] += a.z * wa.w;
      acc_a[3][0] += a.w * wa.x; acc_a[3][1] += a.w * wa.y; acc_a[3][2] += a.w * wa.z; acc_a[3][3] += a.w * wa.w;
      acc_b[0][0] += a.x * wb.x; acc_b[0][1] += a.x * wb.y; acc_b[0][2] += a.x * wb.z; acc_b[0][3] += a.x * wb.w;
      acc_b[1][0] += a.y * wb.x; acc_b[1][1] += a.y * wb.y; acc_b[1][2] += a.y * wb.z; acc_b[1][3] += a.y * wb.w;
      acc_b[2][0] += a.z * wb.x; acc_b[2][1] += a.z * wb.y; acc_b[2][2] += a.z * wb.z; acc_b[2][3] += a.z * wb.w;
      acc_b[3][0] += a.w * wb.x; acc_b[3][1] += a.w * wb.y; acc_b[3][2] += a.w * wb.z; acc_b[3][3] += a.w * wb.w;
    }
    __syncthreads();
  }
  float4 bj = *(const float4*)(aggb + tx * 4);
  #pragma unroll
  for (int i = 0; i < 4; ++i) {
    int node = n0 + tn * 4 + i;
    if (node < N && deg[node] > 0) {
      float sc = scale[node];
      float4* hp = (float4*)(hidden + (size_t)node * 64 + tx * 4);
      float4 h = *hp;
      h.x += acc_a[i][0] + sc * acc_b[i][0] + bj.x;
      h.y += acc_a[i][1] + sc * acc_b[i][1] + bj.y;
      h.z += acc_a[i][2] + sc * acc_b[i][2] + bj.z;
      h.w += acc_a[i][3] + sc * acc_b[i][3] + bj.w;
      *hp = h;
    }
  }
}

// ---------------- score: register-blocked tile kernel ----------------
// 64 nodes per block, 256 threads. lane = node (0..63), g = tid>>6 (0..3).
// Phase A: heur = H @ lin_W[0:64] + cq, x = H * heur (16 indep acc/thread).
// Phase B: h1 = relu(x @ W1 + b1), p = sum(h1 * W2) (32 indep acc/thread).
// LDS layout (floats), phase-overlapped:
//   X  @ 0     (64*65 = 4160)
//   H  @ 4160  (4160)           } phase A
//   WA @ 8320  (4096)           } phase A (lin_W rows 0..63)
//   W1 @ 4160  (8192)           } phase B (overwrites H+WA after sync)
//   sW2 @ 12416 (128), sb1 @ 12544 (128), scq @ 12672 (64), pred @ 12736 (256)
#define SC_LDS 12992
__global__ __launch_bounds__(256) void score2_k(const float* __restrict__ hidden, float* __restrict__ score,
                                                const int* __restrict__ deg, const float* __restrict__ lin_W,
                                                const float* __restrict__ mlp_W1, const float* __restrict__ mlp_b1,
                                                const float* __restrict__ mlp_W2, const float* __restrict__ mlp_b2,
                                                const float* __restrict__ scalars, int N) {
  __shared__ float smem[SC_LDS];
  float* X   = smem;
  float* H   = smem + 4160;
  float* WA  = smem + 8320;
  float* W1s = smem + 4160;
  float* sW2 = smem + 12416;
  float* sb1 = smem + 12544;
  float* scq = smem + 12672;
  float* pred= smem + 12736;

  int t = threadIdx.x;
  int lane = t & 63;        // node within tile
  int g = t >> 6;           // 0..3
  int n0 = blockIdx.x * 64;

  // stage lin_W rows 0..63 (hidden part), smalls
  for (int i = t; i < 1024; i += 256) ((float4*)WA)[i] = ((const float4*)lin_W)[i];
  if (t < 128) { sW2[t] = mlp_W2[t]; sb1[t] = mlp_b1[t]; }
  if (t < 64) scq[t] = scalars[t];
  // stage hidden tile -> H[node][k] with stride 65
  for (int i = t; i < 1024; i += 256) {
    int node = i >> 4;
    int k4 = (i & 15) << 2;
    float4 v = make_float4(0.f, 0.f, 0.f, 0.f);
    if (n0 + node < N) v = ((const float4*)(hidden + (size_t)(n0 + node) * 64))[i & 15];
    float* hp = &H[node * 65 + k4];
    hp[0] = v.x; hp[1] = v.y; hp[2] = v.z; hp[3] = v.w;
  }
  __syncthreads();

  // Phase A: heur (16 outputs j = g*16 + i per thread, node = lane)
  float acc[16];
  #pragma unroll
  for (int i = 0; i < 16; ++i) acc[i] = scq[g * 16 + i];
  #pragma unroll 8
  for (int kk = 0; kk < 64; ++kk) {
    float h = H[lane * 65 + kk];                       // 2-way alias: free
    const float4* wr = (const float4*)&WA[kk * 64 + g * 16];  // broadcast
    float4 w0 = wr[0], w1 = wr[1], w2 = wr[2], w3 = wr[3];
    acc[0]  += h * w0.x; acc[1]  += h * w0.y; acc[2]  += h * w0.z; acc[3]  += h * w0.w;
    acc[4]  += h * w1.x; acc[5]  += h * w1.y; acc[6]  += h * w1.z; acc[7]  += h * w1.w;
    acc[8]  += h * w2.x; acc[9]  += h * w2.y; acc[10] += h * w2.z; acc[11] += h * w2.w;
    acc[12] += h * w3.x; acc[13] += h * w3.y; acc[14] += h * w3.z; acc[15] += h * w3.w;
  }
  // x = H * heur, store to X
  #pragma unroll
  for (int i = 0; i < 16; ++i) {
    int j = g * 16 + i;
    X[lane * 65 + j] = H[lane * 65 + j] * acc[i];
  }
  __syncthreads();  // X complete; H/WA now dead

  // stage W1 (64x128) into the H/WA region
  for (int i = t; i < 2048; i += 256) ((float4*)W1s)[i] = ((const float4*)mlp_W1)[i];
  __syncthreads();

  // Phase B: h1 j2 = g*32 + i, node = lane
  float acc2[32];
  #pragma unroll
  for (int i = 0; i < 32; ++i) acc2[i] = sb1[g * 32 + i];
  #pragma unroll 4
  for (int kk = 0; kk < 64; ++kk) {
    float xv = X[lane * 65 + kk];
    const float4* wr = (const float4*)&W1s[kk * 128 + g * 32];  // broadcast
    #pragma unroll
    for (int s = 0; s < 8; ++s) {
      float4 w = wr[s];
      acc2[s * 4 + 0] += xv * w.x; acc2[s * 4 + 1] += xv * w.y;
      acc2[s * 4 + 2] += xv * w.z; acc2[s * 4 + 3] += xv * w.w;
    }
  }
  float p = 0.f;
  #pragma unroll
  for (int i = 0; i < 32; ++i) p += fmaxf(acc2[i], 0.f) * sW2[g * 32 + i];
  pred[g * 64 + lane] = p;
  __syncthreads();
  if (t < 64) {
    int node = n0 + t;
    if (node < N && deg[node] > 0)
      score[node] = pred[t] + pred[64 + t] + pred[128 + t] + pred[192 + t] + mlp_b2[0];
  }
}

__global__ void out_k(const float* __restrict__ score, const int* __restrict__ t_index,
                      float* __restrict__ out, int T) {
  int i = blockIdx.x * blockDim.x + threadIdx.x;
  if (i < T) out[i] = score[t_index[i]];
}

// ---------------- launch ----------------
extern "C" void kernel_launch(void* const* d_in, const int* in_sizes, int n_in,
                              void* d_out, int out_size, void* d_ws, size_t ws_size,
                              hipStream_t stream) {
  const float* head_embeds = (const float*)d_in[0];
  const float* rel_table   = (const float*)d_in[1];
  const float* rel_W       = (const float*)d_in[2];
  const float* agg_W       = (const float*)d_in[3];
  const float* agg_b       = (const float*)d_in[4];
  const float* lin_W       = (const float*)d_in[5];
  const float* lin_b       = (const float*)d_in[6];
  const float* mlp_W1      = (const float*)d_in[7];
  const float* mlp_b1      = (const float*)d_in[8];
  const float* mlp_W2      = (const float*)d_in[9];
  const float* mlp_b2      = (const float*)d_in[10];
  const int* edge_src      = (const int*)d_in[11];
  const int* edge_dst      = (const int*)d_in[12];
  const int* edge_type     = (const int*)d_in[13];
  const int* head_index    = (const int*)d_in[14];
  const int* r_index       = (const int*)d_in[15];
  const int* t_index       = (const int*)d_in[16];
  int E = in_sizes[11];
  int T = in_sizes[16];
  int N = NN;

  char* w = (char*)d_ws;
  size_t off = 0;
  auto alloc = [&](size_t bytes) {
    void* p = w + off;
    off = (off + bytes + 255) & ~(size_t)255;
    return p;
  };
  int* deg      = (int*)alloc((size_t)N * 4);
  int* start    = (int*)alloc((size_t)N * 4);
  int* cursor   = (int*)alloc((size_t)N * 4);
  float* scale  = (float*)alloc((size_t)N * 4);
  int* counter  = (int*)alloc(4);
  float* logsum = (float*)alloc(4);
  float* scalars= (float*)alloc(66 * 4);
  int2* csr     = (int2*)alloc((size_t)E * 8);
  float* hidden = (float*)alloc((size_t)N * 64 * 4);
  float* score  = (float*)alloc((size_t)N * 4);
  float* LI     = (float*)alloc((size_t)N * 64 * 4);
  float* f1     = (float*)alloc((size_t)N * 256 * 4);
  if (off > ws_size) return;  // workspace too small -> fail loudly via wrong output

  hipMemsetAsync(deg, 0, (size_t)N * 4, stream);
  hipMemsetAsync(counter, 0, 4, stream);
  hipMemsetAsync(logsum, 0, 4, stream);
  hipMemsetAsync(hidden, 0, (size_t)N * 64 * 4, stream);

  count_k<<<(E + 255) / 256, 256, 0, stream>>>(edge_dst, deg, E);
  scan_k<<<(N + 255) / 256, 256, 0, stream>>>(deg, start, cursor, counter, logsum, N);
  scale_k<<<(N + 255) / 256, 256, 0, stream>>>(deg, logsum, scale, N);
  scatter_k<<<(E + 255) / 256, 256, 0, stream>>>(edge_src, edge_dst, edge_type, cursor, csr, E);
  prep_k<<<1, 64, 0, stream>>>(head_embeds, rel_table, lin_W, lin_b, mlp_W1, mlp_b1, mlp_W2, mlp_b2,
                               head_index, r_index, hidden, scalars);
  fill_k<<<(N + 255) / 256, 256, 0, stream>>>(score, scalars, head_index, N);

  for (int l = 0; l < NLAYERS; ++l) {
    gate_k<<<(N * 16 + 255) / 256, 256, 0, stream>>>(hidden, score, LI, N);
    agg_k<<<(N + 3) / 4, 256, 0, stream>>>(LI, csr, start, deg, rel_W + (size_t)l * NREL * 64, f1, N);
    gemm_k<<<(N + 63) / 64, 256, 0, stream>>>(f1, agg_W + (size_t)l * 512 * 64, agg_b + (size_t)l * 64,
                                              scale, deg, hidden, N);
    score2_k<<<(N + 63) / 64, 256, 0, stream>>>(hidden, score, deg, lin_W, mlp_W1, mlp_b1, mlp_W2, mlp_b2,
                                                scalars, N);
  }
  out_k<<<(T + 255) / 256, 256, 0, stream>>>(score, t_index, (float*)d_out, T);
}